// Round 5
// baseline (296.738 us; speedup 1.0000x reference)
//
#include <hip/hip_runtime.h>
#include <hip/hip_bf16.h>

#define B_    16384
#define S_    37
#define F_    17
#define OWN_  9
#define NOUT_ 23
#define OBS_ROW 646   // 38*17

typedef __bf16 bf16x8 __attribute__((ext_vector_type(8)));
typedef __bf16 bf16x4 __attribute__((ext_vector_type(4)));
typedef float  f32x4  __attribute__((ext_vector_type(4)));

#define MFMA(a,b,c) __builtin_amdgcn_mfma_f32_16x16x32_bf16(a, b, c, 0, 0, 0)

// ---- fragment-linear weight layout in ws (bf16 elements) ----
// dst[(k>>3)*(Np*8) + n*8 + (k&7)] = W[k][n]  (zero-padded)
#define W1F_OFF   0        // Np=256, Kp=32   -> 8192
#define W2F_OFF   8192     // Np=256, Kp=256  -> 65536
#define W3F_OFF   73728    // Np=128, Kp=256  -> 32768
#define AW1F_OFF  106496   // Np=256, Kp=160  -> 40960
#define AW2F_OFF  147456   // Np=256, Kp=256  -> 65536
#define AW3F_OFF  212992   // Np=32,  Kp=256  -> 8192
#define VW1F_OFF  221184   // Np=256, Kp=160  -> 40960
#define VW2F_OFF  262144   // Np=256, Kp=256  -> 65536
#define VW3F_OFF  327680   // Np=16,  Kp=256  -> 4096
#define PREP_TOTAL 331776

#define RS_ACT 264
#define RS_XS  40
#define RS_CAT 168

__global__ void prep_kernel(const float* __restrict__ sW1, const float* __restrict__ sW2,
                            const float* __restrict__ sW3, const float* __restrict__ aW1,
                            const float* __restrict__ aW2, const float* __restrict__ aW3,
                            const float* __restrict__ vW1, const float* __restrict__ vW2,
                            const float* __restrict__ vW3, __bf16* __restrict__ ws)
{
    int j = blockIdx.x * 256 + threadIdx.x;
    const float* src; __bf16* dst; int Np, Ks, Ns;
    if (j < 8192)                  { dst = ws + W1F_OFF;  src = sW1; Np = 256; Ks = 17;  Ns = 256; }
    else if ((j -= 8192)  < 65536) { dst = ws + W2F_OFF;  src = sW2; Np = 256; Ks = 256; Ns = 256; }
    else if ((j -= 65536) < 32768) { dst = ws + W3F_OFF;  src = sW3; Np = 128; Ks = 256; Ns = 128; }
    else if ((j -= 32768) < 40960) { dst = ws + AW1F_OFF; src = aW1; Np = 256; Ks = 137; Ns = 256; }
    else if ((j -= 40960) < 65536) { dst = ws + AW2F_OFF; src = aW2; Np = 256; Ks = 256; Ns = 256; }
    else if ((j -= 65536) < 8192)  { dst = ws + AW3F_OFF; src = aW3; Np = 32;  Ks = 256; Ns = 23;  }
    else if ((j -= 8192)  < 40960) { dst = ws + VW1F_OFF; src = vW1; Np = 256; Ks = 137; Ns = 256; }
    else if ((j -= 40960) < 65536) { dst = ws + VW2F_OFF; src = vW2; Np = 256; Ks = 256; Ns = 256; }
    else { j -= 65536;               dst = ws + VW3F_OFF; src = vW3; Np = 16;  Ks = 256; Ns = 1;   }
    const int c = j / (Np * 8), rem = j - c * Np * 8, n = rem >> 3, e = rem & 7, k = c * 8 + e;
    const float v = (k < Ks && n < Ns) ? src[k * Ns + n] : 0.f;
    dst[j] = (__bf16)v;
}

// 512 threads = 8 waves; block = 16 batch rows; M-tile = 64 tokens (16b x 4s),
// 10 iters, 2 barriers/iter. TRANSPOSED MFMA orientation: A = W^T frags
// (registers), B = act^T frags (row-major LDS [token][264]) -> C rows = out
// cols, cols = tokens -> epilogue packs 4 consecutive h per lane = ds_write_b64
// (round 4's scalar b16 writes had 16-way conflicts on 4 banks).
// L1/L2: waves = 4 col-groups(64) x 2 token-halves (A-reuse x2);
// L3: 8 waves x 16 cols, all tokens (keeps pooling wave-local).
__global__ __launch_bounds__(512, 2) void fused_kernel(
    const float* __restrict__ obs,
    const float* __restrict__ sb1, const float* __restrict__ sb2, const float* __restrict__ sb3,
    const float* __restrict__ ab1, const float* __restrict__ ab2, const float* __restrict__ ab3,
    const float* __restrict__ vb1, const float* __restrict__ vb2, const float* __restrict__ vb3,
    const __bf16* __restrict__ ws, float* __restrict__ out)
{
    __shared__ __align__(16) __bf16 act1[64 * RS_ACT];
    __shared__ __align__(16) __bf16 act2[64 * RS_ACT];
    __shared__ __align__(16) __bf16 xs[2][64 * RS_XS];
    __shared__ float sm[2][64];
    __shared__ __align__(16) float sbias[640];           // sb1|sb2|sb3
    __shared__ __align__(16) __bf16 catf[16 * RS_CAT];

    const __bf16* W1f  = ws + W1F_OFF;
    const __bf16* W2f  = ws + W2F_OFF;
    const __bf16* W3f  = ws + W3F_OFF;

    const int tid  = threadIdx.x;
    const int wave = tid >> 6;
    const int lane = tid & 63;
    const int q    = lane >> 4;
    const int l16  = lane & 15;
    const int wg   = wave & 3;          // col-group for L1/L2 (64 cols)
    const int th   = wave >> 2;         // token-half for L1/L2
    const int tb   = th * 32;
    const int b0   = blockIdx.x * 16;
    const f32x4 z4 = {0.f, 0.f, 0.f, 0.f};

    // stage biases into LDS; zero xs (pad cols 17..31 stay zero forever)
    for (int i = tid; i < 640; i += 512)
        sbias[i] = (i < 256) ? sb1[i] : (i < 512 ? sb2[i - 256] : sb3[i - 512]);
    for (int i = tid; i < 2 * 64 * RS_XS; i += 512) xs[0][i] = (__bf16)0.f;

    // ---- loop-invariant weight fragments (A-operand = W^T) ----
    bf16x8 w1f[4], w2f[8][4], w3f[8];
    #pragma unroll
    for (int nt = 0; nt < 4; ++nt) {
        const int n = wg * 64 + nt * 16 + l16;
        w1f[nt] = *(const bf16x8*)(W1f + ((size_t)q * 256 + n) * 8);
        #pragma unroll
        for (int k = 0; k < 8; ++k)
            w2f[k][nt] = *(const bf16x8*)(W2f + ((size_t)(k * 4 + q) * 256 + n) * 8);
    }
    #pragma unroll
    for (int k = 0; k < 8; ++k)
        w3f[k] = *(const bf16x8*)(W3f + ((size_t)(k * 4 + q) * 128 + wave * 16 + l16) * 8);

    __syncthreads();  // zeros/bias visible before preload stores

    // preload iter 0: token row = lane (b = lane&15, s_local = lane>>4)
    if (wave == 7) {
        const float* p = obs + (size_t)(b0 + (lane & 15)) * OBS_ROW + ((lane >> 4) + 1) * F_;
        float smv = 0.f;
        #pragma unroll
        for (int c = 0; c < F_; ++c) {
            const float v = p[c];
            smv += fabsf(v);
            xs[0][lane * RS_XS + c] = (__bf16)v;
        }
        sm[0][lane] = smv;
    }
    __syncthreads();  // xs0/sm0 ready

    f32x4 vsum = z4;

    for (int it = 0; it < 10; ++it) {
        const __bf16* xc = xs[it & 1];
        __bf16*       xn = xs[1 - (it & 1)];
        const float* smc = sm[it & 1];
        float*       smn = sm[1 - (it & 1)];

        // phase A: wave7 loads obs(it+1) -> xn; all waves L1
        if (it < 9 && wave == 7) {
            const int s = 4 * (it + 1) + (lane >> 4);
            if (s < S_) {
                const float* p = obs + (size_t)(b0 + (lane & 15)) * OBS_ROW + (s + 1) * F_;
                float smv = 0.f;
                #pragma unroll
                for (int c = 0; c < F_; ++c) {
                    const float v = p[c];
                    smv += fabsf(v);
                    xn[lane * RS_XS + c] = (__bf16)v;
                }
                smn[lane] = smv;
            } else {
                smn[lane] = 0.f;
            }
        }

        // ---- L1: act1[token][n] for tokens tb..tb+31, cols wg*64..+63 ----
        {
            bf16x8 xa[2];
            #pragma unroll
            for (int tt = 0; tt < 2; ++tt)
                xa[tt] = *(const bf16x8*)(xc + (tb + tt * 16 + l16) * RS_XS + q * 8);
            #pragma unroll
            for (int nt = 0; nt < 4; ++nt) {
                const int n0 = wg * 64 + nt * 16 + q * 4;
                const f32x4 bb = *(const f32x4*)(sbias + n0);
                #pragma unroll
                for (int tt = 0; tt < 2; ++tt) {
                    const f32x4 h = MFMA(w1f[nt], xa[tt], z4);
                    bf16x4 o;
                    #pragma unroll
                    for (int r = 0; r < 4; ++r) {
                        float v = h[r] + bb[r];
                        o[r] = (__bf16)(v > 0.f ? v : 0.f);
                    }
                    *(bf16x4*)(act1 + (tb + tt * 16 + l16) * RS_ACT + n0) = o;
                }
            }
        }
        __syncthreads();  // B1: act1 ready

        // ---- L2: act2 = relu(act1 @ W2 + b2), same wave split ----
        {
            f32x4 acc[4][2];
            #pragma unroll
            for (int nt = 0; nt < 4; ++nt) { acc[nt][0] = z4; acc[nt][1] = z4; }
            #pragma unroll
            for (int k = 0; k < 8; ++k) {
                const bf16x8 a0 = *(const bf16x8*)(act1 + (tb + l16) * RS_ACT + k * 32 + q * 8);
                const bf16x8 a1 = *(const bf16x8*)(act1 + (tb + 16 + l16) * RS_ACT + k * 32 + q * 8);
                #pragma unroll
                for (int nt = 0; nt < 4; ++nt) {
                    acc[nt][0] = MFMA(w2f[k][nt], a0, acc[nt][0]);
                    acc[nt][1] = MFMA(w2f[k][nt], a1, acc[nt][1]);
                }
            }
            #pragma unroll
            for (int nt = 0; nt < 4; ++nt) {
                const int n0 = wg * 64 + nt * 16 + q * 4;
                const f32x4 bb = *(const f32x4*)(sbias + 256 + n0);
                #pragma unroll
                for (int tt = 0; tt < 2; ++tt) {
                    bf16x4 o;
                    #pragma unroll
                    for (int r = 0; r < 4; ++r) {
                        float v = acc[nt][tt][r] + bb[r];
                        o[r] = (__bf16)(v > 0.f ? v : 0.f);
                    }
                    *(bf16x4*)(act2 + (tb + tt * 16 + l16) * RS_ACT + n0) = o;
                }
            }
        }
        __syncthreads();  // B2: act2 ready

        // ---- L3: 16 cols/wave, all 64 tokens; relu, mask, pool ----
        {
            f32x4 h3[4];
            #pragma unroll
            for (int m = 0; m < 4; ++m) h3[m] = z4;
            #pragma unroll
            for (int k = 0; k < 8; ++k) {
                #pragma unroll
                for (int m = 0; m < 4; ++m) {
                    const bf16x8 a = *(const bf16x8*)(act2 + (m * 16 + l16) * RS_ACT + k * 32 + q * 8);
                    h3[m] = MFMA(w3f[k], a, h3[m]);
                }
            }
            const f32x4 bb = *(const f32x4*)(sbias + 512 + wave * 16 + q * 4);
            #pragma unroll
            for (int m = 0; m < 4; ++m) {
                const float mv = smc[m * 16 + l16];
                #pragma unroll
                for (int r = 0; r < 4; ++r) {
                    float v = h3[m][r] + bb[r];
                    v = v > 0.f ? v : 0.f;
                    vsum[r] += (mv != 0.f) ? v : 0.f;
                }
            }
        }
    }

    // lane holds pooled sum for (b = l16, h = wave*16 + q*4 + r)
    {
        bf16x4 o;
        #pragma unroll
        for (int r = 0; r < 4; ++r) o[r] = (__bf16)vsum[r];
        *(bf16x4*)(catf + l16 * RS_CAT + wave * 16 + q * 4) = o;
    }
    // s_own -> catf[:,128..136], zero 137..159 (160..167 pad never read)
    if (tid < 16) {
        const float* p = obs + (size_t)(b0 + tid) * OBS_ROW;
        #pragma unroll
        for (int j = 0; j < OWN_; ++j) catf[tid * RS_CAT + 128 + j] = (__bf16)p[j];
        #pragma unroll
        for (int j = OWN_; j < 32; ++j) catf[tid * RS_CAT + 128 + j] = (__bf16)0.f;
    }
    __syncthreads();  // catf ready; act1/act2 free

    // ---- heads: waves 0-3 actor, 4-7 value; col-group wg*64 each ----
    const bool  actor = (wave < 4);
    const int   drow  = actor ? l16 : (16 + l16);
    const __bf16* HW1 = ws + (actor ? AW1F_OFF : VW1F_OFF);
    const __bf16* HW2 = ws + (actor ? AW2F_OFF : VW2F_OFF);
    const float* hb1  = actor ? ab1 : vb1;
    const float* hb2  = actor ? ab2 : vb2;

    // head L1: K=160 (5 windows), cat^T as B
    {
        f32x4 acc[4];
        #pragma unroll
        for (int nt = 0; nt < 4; ++nt) acc[nt] = z4;
        #pragma unroll
        for (int k = 0; k < 5; ++k) {
            const bf16x8 ca = *(const bf16x8*)(catf + l16 * RS_CAT + k * 32 + q * 8);
            #pragma unroll
            for (int nt = 0; nt < 4; ++nt) {
                const bf16x8 wf = *(const bf16x8*)(HW1 + ((size_t)(k * 4 + q) * 256 + wg * 64 + nt * 16 + l16) * 8);
                acc[nt] = MFMA(wf, ca, acc[nt]);
            }
        }
        #pragma unroll
        for (int nt = 0; nt < 4; ++nt) {
            const int n0 = wg * 64 + nt * 16 + q * 4;
            const f32x4 bb = *(const f32x4*)(hb1 + n0);
            bf16x4 o;
            #pragma unroll
            for (int r = 0; r < 4; ++r) {
                float v = acc[nt][r] + bb[r];
                o[r] = (__bf16)(v > 0.f ? v : 0.f);
            }
            *(bf16x4*)(act1 + drow * RS_ACT + n0) = o;
        }
    }
    __syncthreads();

    // head L2: K=256 (8 windows)
    {
        f32x4 acc[4];
        #pragma unroll
        for (int nt = 0; nt < 4; ++nt) acc[nt] = z4;
        #pragma unroll
        for (int k = 0; k < 8; ++k) {
            const bf16x8 a = *(const bf16x8*)(act1 + drow * RS_ACT + k * 32 + q * 8);
            #pragma unroll
            for (int nt = 0; nt < 4; ++nt) {
                const bf16x8 wf = *(const bf16x8*)(HW2 + ((size_t)(k * 4 + q) * 256 + wg * 64 + nt * 16 + l16) * 8);
                acc[nt] = MFMA(wf, a, acc[nt]);
            }
        }
        #pragma unroll
        for (int nt = 0; nt < 4; ++nt) {
            const int n0 = wg * 64 + nt * 16 + q * 4;
            const f32x4 bb = *(const f32x4*)(hb2 + n0);
            bf16x4 o;
            #pragma unroll
            for (int r = 0; r < 4; ++r) {
                float v = acc[nt][r] + bb[r];
                o[r] = (__bf16)(v > 0.f ? v : 0.f);
            }
            *(bf16x4*)(act2 + drow * RS_ACT + n0) = o;
        }
    }
    __syncthreads();

    // head L3
    if (wave < 2) {       // actor logits: rows = logit cols, wtile = wave
        f32x4 acc = z4;
        #pragma unroll
        for (int k = 0; k < 8; ++k) {
            const bf16x8 a  = *(const bf16x8*)(act2 + l16 * RS_ACT + k * 32 + q * 8);
            const bf16x8 wf = *(const bf16x8*)(ws + AW3F_OFF + ((size_t)(k * 4 + q) * 32 + wave * 16 + l16) * 8);
            acc = MFMA(wf, a, acc);
        }
        #pragma unroll
        for (int r = 0; r < 4; ++r) {
            const int logit = wave * 16 + q * 4 + r;
            if (logit < NOUT_)
                out[(size_t)(b0 + l16) * NOUT_ + logit] = acc[r] + ab3[logit];
        }
    } else if (wave == 4) {  // value head: row 0 of vW3
        f32x4 acc = z4;
        #pragma unroll
        for (int k = 0; k < 8; ++k) {
            const bf16x8 a  = *(const bf16x8*)(act2 + (16 + l16) * RS_ACT + k * 32 + q * 8);
            const bf16x8 wf = *(const bf16x8*)(ws + VW3F_OFF + ((size_t)(k * 4 + q) * 16 + l16) * 8);
            acc = MFMA(wf, a, acc);
        }
        if (q == 0)
            out[(size_t)B_ * NOUT_ + b0 + l16] = acc[0] + vb3[0];
    }
}

extern "C" void kernel_launch(void* const* d_in, const int* in_sizes, int n_in,
                              void* d_out, int out_size, void* d_ws, size_t ws_size,
                              hipStream_t stream)
{
    const float* obs = (const float*)d_in[0];
    const float* sW1 = (const float*)d_in[1];
    const float* sb1 = (const float*)d_in[2];
    const float* sW2 = (const float*)d_in[3];
    const float* sb2 = (const float*)d_in[4];
    const float* sW3 = (const float*)d_in[5];
    const float* sb3 = (const float*)d_in[6];
    const float* aW1 = (const float*)d_in[7];
    const float* ab1 = (const float*)d_in[8];
    const float* aW2 = (const float*)d_in[9];
    const float* ab2 = (const float*)d_in[10];
    const float* aW3 = (const float*)d_in[11];
    const float* ab3 = (const float*)d_in[12];
    const float* vW1 = (const float*)d_in[13];
    const float* vb1 = (const float*)d_in[14];
    const float* vW2 = (const float*)d_in[15];
    const float* vb2 = (const float*)d_in[16];
    const float* vW3 = (const float*)d_in[17];
    const float* vb3 = (const float*)d_in[18];

    __bf16* ws = (__bf16*)d_ws;
    float* out = (float*)d_out;

    hipLaunchKernelGGL(prep_kernel, dim3(PREP_TOTAL / 256), dim3(256), 0, stream,
                       sW1, sW2, sW3, aW1, aW2, aW3, vW1, vW2, vW3, ws);
    hipLaunchKernelGGL(fused_kernel, dim3(B_ / 16), dim3(512), 0, stream,
                       obs, sb1, sb2, sb3, ab1, ab2, ab3, vb1, vb2, vb3,
                       (const __bf16*)ws, out);
}

// Round 6
// 296.676 us; speedup vs baseline: 1.0002x; 1.0002x over previous
//
#include <hip/hip_runtime.h>
#include <hip/hip_bf16.h>

#define B_    16384
#define S_    37
#define F_    17
#define OWN_  9
#define NOUT_ 23
#define OBS_ROW 646   // 38*17

typedef __bf16 bf16x8 __attribute__((ext_vector_type(8)));
typedef __bf16 bf16x4 __attribute__((ext_vector_type(4)));
typedef float  f32x4  __attribute__((ext_vector_type(4)));

#define MFMA(a,b,c) __builtin_amdgcn_mfma_f32_16x16x32_bf16(a, b, c, 0, 0, 0)

// ---- fragment-linear weight layout in ws (bf16 elements) ----
// dst[(k>>3)*(Np*8) + n*8 + (k&7)] = W[k][n]  (zero-padded)
#define W1F_OFF   0        // Np=256, Kp=32   -> 8192
#define W2F_OFF   8192     // Np=256, Kp=256  -> 65536
#define W3F_OFF   73728    // Np=128, Kp=256  -> 32768
#define AW1F_OFF  106496   // Np=256, Kp=160  -> 40960
#define AW2F_OFF  147456   // Np=256, Kp=256  -> 65536
#define AW3F_OFF  212992   // Np=32,  Kp=256  -> 8192
#define VW1F_OFF  221184   // Np=256, Kp=160  -> 40960
#define VW2F_OFF  262144   // Np=256, Kp=256  -> 65536
#define VW3F_OFF  327680   // Np=16,  Kp=256  -> 4096
#define PREP_TOTAL 331776

#define RS_CAT 168

__global__ void prep_kernel(const float* __restrict__ sW1, const float* __restrict__ sW2,
                            const float* __restrict__ sW3, const float* __restrict__ aW1,
                            const float* __restrict__ aW2, const float* __restrict__ aW3,
                            const float* __restrict__ vW1, const float* __restrict__ vW2,
                            const float* __restrict__ vW3, __bf16* __restrict__ ws)
{
    int j = blockIdx.x * 256 + threadIdx.x;
    const float* src; __bf16* dst; int Np, Ks, Ns;
    if (j < 8192)                  { dst = ws + W1F_OFF;  src = sW1; Np = 256; Ks = 17;  Ns = 256; }
    else if ((j -= 8192)  < 65536) { dst = ws + W2F_OFF;  src = sW2; Np = 256; Ks = 256; Ns = 256; }
    else if ((j -= 65536) < 32768) { dst = ws + W3F_OFF;  src = sW3; Np = 128; Ks = 256; Ns = 128; }
    else if ((j -= 32768) < 40960) { dst = ws + AW1F_OFF; src = aW1; Np = 256; Ks = 137; Ns = 256; }
    else if ((j -= 40960) < 65536) { dst = ws + AW2F_OFF; src = aW2; Np = 256; Ks = 256; Ns = 256; }
    else if ((j -= 65536) < 8192)  { dst = ws + AW3F_OFF; src = aW3; Np = 32;  Ks = 256; Ns = 23;  }
    else if ((j -= 8192)  < 40960) { dst = ws + VW1F_OFF; src = vW1; Np = 256; Ks = 137; Ns = 256; }
    else if ((j -= 40960) < 65536) { dst = ws + VW2F_OFF; src = vW2; Np = 256; Ks = 256; Ns = 256; }
    else { j -= 65536;               dst = ws + VW3F_OFF; src = vW3; Np = 16;  Ks = 256; Ns = 1;   }
    const int c = j / (Np * 8), rem = j - c * Np * 8, n = rem >> 3, e = rem & 7, k = c * 8 + e;
    const float v = (k < Ks && n < Ns) ? src[k * Ns + n] : 0.f;
    dst[j] = (__bf16)v;
}

// 512 threads = 8 waves; block = 16 batch rows; M-tile = 64 tokens (16b x 4s),
// 10 iters, 2 barriers/iter. Transposed MFMA (A = W^T regs, C rows = h-cols)
// + FRAG-MAJOR LDS act layout [kchunk][token][8]:
//   reads  (k8*64+token)*8  -> lane-consecutive 16B, conflict-free (r4 pattern)
//   writes 4 consecutive h per lane -> ds_write_b64, 2 dwords/bank, free
// (r5's row-major layout put an 8-way conflict on every hot b128 read: 2.25e7
// conflict-cycles ~= the whole gap to the LDS floor).
__global__ __launch_bounds__(512, 2) void fused_kernel(
    const float* __restrict__ obs,
    const float* __restrict__ sb1, const float* __restrict__ sb2, const float* __restrict__ sb3,
    const float* __restrict__ ab1, const float* __restrict__ ab2, const float* __restrict__ ab3,
    const float* __restrict__ vb1, const float* __restrict__ vb2, const float* __restrict__ vb3,
    const __bf16* __restrict__ ws, float* __restrict__ out)
{
    __shared__ __align__(16) __bf16 act1[32 * 64 * 8];   // [32 kch][64 tok][8]
    __shared__ __align__(16) __bf16 act2[32 * 64 * 8];
    __shared__ __align__(16) __bf16 xs[2][4 * 64 * 8];   // [4 kch][64 tok][8]
    __shared__ float sm[2][64];
    __shared__ __align__(16) float sbias[640];           // sb1|sb2|sb3
    __shared__ __align__(16) __bf16 catf[16 * RS_CAT];

    const __bf16* W1f  = ws + W1F_OFF;
    const __bf16* W2f  = ws + W2F_OFF;
    const __bf16* W3f  = ws + W3F_OFF;

    const int tid  = threadIdx.x;
    const int wave = tid >> 6;
    const int lane = tid & 63;
    const int q    = lane >> 4;
    const int l16  = lane & 15;
    const int wg   = wave & 3;          // col-group for L1/L2 (64 cols)
    const int th   = wave >> 2;         // token-half for L1/L2
    const int tb   = th * 32;
    const int b0   = blockIdx.x * 16;
    const f32x4 z4 = {0.f, 0.f, 0.f, 0.f};

    // stage biases; zero xs (chunk 3 = elems 24..31 stays zero forever)
    for (int i = tid; i < 640; i += 512)
        sbias[i] = (i < 256) ? sb1[i] : (i < 512 ? sb2[i - 256] : sb3[i - 512]);
    for (int i = tid; i < 2 * 2048; i += 512) xs[0][i] = (__bf16)0.f;

    // ---- loop-invariant weight fragments (A-operand = W^T) ----
    bf16x8 w1f[4], w2f[8][4], w3f[8];
    #pragma unroll
    for (int nt = 0; nt < 4; ++nt) {
        const int n = wg * 64 + nt * 16 + l16;
        w1f[nt] = *(const bf16x8*)(W1f + ((size_t)q * 256 + n) * 8);
        #pragma unroll
        for (int k = 0; k < 8; ++k)
            w2f[k][nt] = *(const bf16x8*)(W2f + ((size_t)(k * 4 + q) * 256 + n) * 8);
    }
    #pragma unroll
    for (int k = 0; k < 8; ++k)
        w3f[k] = *(const bf16x8*)(W3f + ((size_t)(k * 4 + q) * 128 + wave * 16 + l16) * 8);

    __syncthreads();  // zeros/bias visible before preload stores

    // preload iter 0: token = lane (b = lane&15, s_local = lane>>4)
    if (wave == 7) {
        const float* p = obs + (size_t)(b0 + (lane & 15)) * OBS_ROW + ((lane >> 4) + 1) * F_;
        float smv = 0.f;
        bf16x8 v0, v1, v2;
        #pragma unroll
        for (int c = 0; c < 8; ++c) { const float v = p[c];     smv += fabsf(v); v0[c] = (__bf16)v; }
        #pragma unroll
        for (int c = 0; c < 8; ++c) { const float v = p[8 + c]; smv += fabsf(v); v1[c] = (__bf16)v; }
        { const float v = p[16]; smv += fabsf(v); v2[0] = (__bf16)v; }
        #pragma unroll
        for (int c = 1; c < 8; ++c) v2[c] = (__bf16)0.f;
        *(bf16x8*)(xs[0] + (0 * 64 + lane) * 8) = v0;
        *(bf16x8*)(xs[0] + (1 * 64 + lane) * 8) = v1;
        *(bf16x8*)(xs[0] + (2 * 64 + lane) * 8) = v2;
        sm[0][lane] = smv;
    }
    __syncthreads();  // xs0/sm0 ready

    f32x4 vsum = z4;

    for (int it = 0; it < 10; ++it) {
        const __bf16* xc = xs[it & 1];
        __bf16*       xn = xs[1 - (it & 1)];
        const float* smc = sm[it & 1];
        float*       smn = sm[1 - (it & 1)];

        // phase A: wave7 loads obs(it+1) -> xn; all waves L1
        if (it < 9 && wave == 7) {
            const int s = 4 * (it + 1) + (lane >> 4);
            if (s < S_) {
                const float* p = obs + (size_t)(b0 + (lane & 15)) * OBS_ROW + (s + 1) * F_;
                float smv = 0.f;
                bf16x8 v0, v1, v2;
                #pragma unroll
                for (int c = 0; c < 8; ++c) { const float v = p[c];     smv += fabsf(v); v0[c] = (__bf16)v; }
                #pragma unroll
                for (int c = 0; c < 8; ++c) { const float v = p[8 + c]; smv += fabsf(v); v1[c] = (__bf16)v; }
                { const float v = p[16]; smv += fabsf(v); v2[0] = (__bf16)v; }
                #pragma unroll
                for (int c = 1; c < 8; ++c) v2[c] = (__bf16)0.f;
                *(bf16x8*)(xn + (0 * 64 + lane) * 8) = v0;
                *(bf16x8*)(xn + (1 * 64 + lane) * 8) = v1;
                *(bf16x8*)(xn + (2 * 64 + lane) * 8) = v2;
                smn[lane] = smv;
            } else {
                smn[lane] = 0.f;   // stale token row masked out
            }
        }

        // ---- L1: tokens tb..tb+31, cols wg*64..+63 -> act1 ----
        {
            bf16x8 xa[2];
            #pragma unroll
            for (int tt = 0; tt < 2; ++tt)
                xa[tt] = *(const bf16x8*)(xc + (q * 64 + tb + tt * 16 + l16) * 8);
            #pragma unroll
            for (int nt = 0; nt < 4; ++nt) {
                const int n0 = wg * 64 + nt * 16 + q * 4;
                const int c = n0 >> 3, e = n0 & 7;
                const f32x4 bb = *(const f32x4*)(sbias + n0);
                #pragma unroll
                for (int tt = 0; tt < 2; ++tt) {
                    const f32x4 h = MFMA(w1f[nt], xa[tt], z4);
                    bf16x4 o;
                    #pragma unroll
                    for (int r = 0; r < 4; ++r) {
                        float v = h[r] + bb[r];
                        o[r] = (__bf16)(v > 0.f ? v : 0.f);
                    }
                    *(bf16x4*)(act1 + (c * 64 + tb + tt * 16 + l16) * 8 + e) = o;
                }
            }
        }
        __syncthreads();  // B1: act1 ready

        // ---- L2: act2 = relu(act1 @ W2 + b2), same wave split ----
        {
            f32x4 acc[4][2];
            #pragma unroll
            for (int nt = 0; nt < 4; ++nt) { acc[nt][0] = z4; acc[nt][1] = z4; }
            #pragma unroll
            for (int k = 0; k < 8; ++k) {
                const int k8 = k * 4 + q;
                const bf16x8 a0 = *(const bf16x8*)(act1 + (k8 * 64 + tb + l16) * 8);
                const bf16x8 a1 = *(const bf16x8*)(act1 + (k8 * 64 + tb + 16 + l16) * 8);
                #pragma unroll
                for (int nt = 0; nt < 4; ++nt) {
                    acc[nt][0] = MFMA(w2f[k][nt], a0, acc[nt][0]);
                    acc[nt][1] = MFMA(w2f[k][nt], a1, acc[nt][1]);
                }
            }
            #pragma unroll
            for (int nt = 0; nt < 4; ++nt) {
                const int n0 = wg * 64 + nt * 16 + q * 4;
                const int c = n0 >> 3, e = n0 & 7;
                const f32x4 bb = *(const f32x4*)(sbias + 256 + n0);
                #pragma unroll
                for (int tt = 0; tt < 2; ++tt) {
                    bf16x4 o;
                    #pragma unroll
                    for (int r = 0; r < 4; ++r) {
                        float v = acc[nt][tt][r] + bb[r];
                        o[r] = (__bf16)(v > 0.f ? v : 0.f);
                    }
                    *(bf16x4*)(act2 + (c * 64 + tb + tt * 16 + l16) * 8 + e) = o;
                }
            }
        }
        __syncthreads();  // B2: act2 ready

        // ---- L3: 16 cols/wave, all 64 tokens; relu, mask, pool ----
        {
            f32x4 h3[4];
            #pragma unroll
            for (int m = 0; m < 4; ++m) h3[m] = z4;
            #pragma unroll
            for (int k = 0; k < 8; ++k) {
                const int k8 = k * 4 + q;
                #pragma unroll
                for (int m = 0; m < 4; ++m) {
                    const bf16x8 a = *(const bf16x8*)(act2 + (k8 * 64 + m * 16 + l16) * 8);
                    h3[m] = MFMA(w3f[k], a, h3[m]);
                }
            }
            const f32x4 bb = *(const f32x4*)(sbias + 512 + wave * 16 + q * 4);
            #pragma unroll
            for (int m = 0; m < 4; ++m) {
                const float mv = smc[m * 16 + l16];
                #pragma unroll
                for (int r = 0; r < 4; ++r) {
                    float v = h3[m][r] + bb[r];
                    v = v > 0.f ? v : 0.f;
                    vsum[r] += (mv != 0.f) ? v : 0.f;
                }
            }
        }
    }

    // lane holds pooled sum for (b = l16, h = wave*16 + q*4 + r)
    {
        bf16x4 o;
        #pragma unroll
        for (int r = 0; r < 4; ++r) o[r] = (__bf16)vsum[r];
        *(bf16x4*)(catf + l16 * RS_CAT + wave * 16 + q * 4) = o;
    }
    // s_own -> catf[:,128..136], zero 137..159 (160..167 pad never read)
    if (tid < 16) {
        const float* p = obs + (size_t)(b0 + tid) * OBS_ROW;
        #pragma unroll
        for (int j = 0; j < OWN_; ++j) catf[tid * RS_CAT + 128 + j] = (__bf16)p[j];
        #pragma unroll
        for (int j = OWN_; j < 32; ++j) catf[tid * RS_CAT + 128 + j] = (__bf16)0.f;
    }
    __syncthreads();  // catf ready; act1/act2 free

    // ---- heads: waves 0-3 actor, 4-7 value; col-group wg*64 each ----
    const bool  actor = (wave < 4);
    const int   drow  = actor ? l16 : (16 + l16);
    const __bf16* HW1 = ws + (actor ? AW1F_OFF : VW1F_OFF);
    const __bf16* HW2 = ws + (actor ? AW2F_OFF : VW2F_OFF);
    const float* hb1  = actor ? ab1 : vb1;
    const float* hb2  = actor ? ab2 : vb2;

    // head L1: K=160 (5 windows), cat^T as B
    {
        f32x4 acc[4];
        #pragma unroll
        for (int nt = 0; nt < 4; ++nt) acc[nt] = z4;
        #pragma unroll
        for (int k = 0; k < 5; ++k) {
            const bf16x8 ca = *(const bf16x8*)(catf + l16 * RS_CAT + k * 32 + q * 8);
            #pragma unroll
            for (int nt = 0; nt < 4; ++nt) {
                const bf16x8 wf = *(const bf16x8*)(HW1 + ((size_t)(k * 4 + q) * 256 + wg * 64 + nt * 16 + l16) * 8);
                acc[nt] = MFMA(wf, ca, acc[nt]);
            }
        }
        #pragma unroll
        for (int nt = 0; nt < 4; ++nt) {
            const int n0 = wg * 64 + nt * 16 + q * 4;
            const int c = n0 >> 3, e = n0 & 7;
            const f32x4 bb = *(const f32x4*)(hb1 + n0);
            bf16x4 o;
            #pragma unroll
            for (int r = 0; r < 4; ++r) {
                float v = acc[nt][r] + bb[r];
                o[r] = (__bf16)(v > 0.f ? v : 0.f);
            }
            *(bf16x4*)(act1 + (c * 64 + drow) * 8 + e) = o;
        }
    }
    __syncthreads();

    // head L2: K=256 (8 windows)
    {
        f32x4 acc[4];
        #pragma unroll
        for (int nt = 0; nt < 4; ++nt) acc[nt] = z4;
        #pragma unroll
        for (int k = 0; k < 8; ++k) {
            const int k8 = k * 4 + q;
            const bf16x8 a = *(const bf16x8*)(act1 + (k8 * 64 + drow) * 8);
            #pragma unroll
            for (int nt = 0; nt < 4; ++nt) {
                const bf16x8 wf = *(const bf16x8*)(HW2 + ((size_t)k8 * 256 + wg * 64 + nt * 16 + l16) * 8);
                acc[nt] = MFMA(wf, a, acc[nt]);
            }
        }
        #pragma unroll
        for (int nt = 0; nt < 4; ++nt) {
            const int n0 = wg * 64 + nt * 16 + q * 4;
            const int c = n0 >> 3, e = n0 & 7;
            const f32x4 bb = *(const f32x4*)(hb2 + n0);
            bf16x4 o;
            #pragma unroll
            for (int r = 0; r < 4; ++r) {
                float v = acc[nt][r] + bb[r];
                o[r] = (__bf16)(v > 0.f ? v : 0.f);
            }
            *(bf16x4*)(act2 + (c * 64 + drow) * 8 + e) = o;
        }
    }
    __syncthreads();

    // head L3
    if (wave < 2) {       // actor logits
        f32x4 acc = z4;
        #pragma unroll
        for (int k = 0; k < 8; ++k) {
            const int k8 = k * 4 + q;
            const bf16x8 a  = *(const bf16x8*)(act2 + (k8 * 64 + l16) * 8);
            const bf16x8 wf = *(const bf16x8*)(ws + AW3F_OFF + ((size_t)k8 * 32 + wave * 16 + l16) * 8);
            acc = MFMA(wf, a, acc);
        }
        #pragma unroll
        for (int r = 0; r < 4; ++r) {
            const int logit = wave * 16 + q * 4 + r;
            if (logit < NOUT_)
                out[(size_t)(b0 + l16) * NOUT_ + logit] = acc[r] + ab3[logit];
        }
    } else if (wave == 4) {  // value head
        f32x4 acc = z4;
        #pragma unroll
        for (int k = 0; k < 8; ++k) {
            const int k8 = k * 4 + q;
            const bf16x8 a  = *(const bf16x8*)(act2 + (k8 * 64 + 16 + l16) * 8);
            const bf16x8 wf = *(const bf16x8*)(ws + VW3F_OFF + ((size_t)k8 * 16 + l16) * 8);
            acc = MFMA(wf, a, acc);
        }
        if (q == 0)
            out[(size_t)B_ * NOUT_ + b0 + l16] = acc[0] + vb3[0];
    }
}

extern "C" void kernel_launch(void* const* d_in, const int* in_sizes, int n_in,
                              void* d_out, int out_size, void* d_ws, size_t ws_size,
                              hipStream_t stream)
{
    const float* obs = (const float*)d_in[0];
    const float* sW1 = (const float*)d_in[1];
    const float* sb1 = (const float*)d_in[2];
    const float* sW2 = (const float*)d_in[3];
    const float* sb2 = (const float*)d_in[4];
    const float* sW3 = (const float*)d_in[5];
    const float* sb3 = (const float*)d_in[6];
    const float* aW1 = (const float*)d_in[7];
    const float* ab1 = (const float*)d_in[8];
    const float* aW2 = (const float*)d_in[9];
    const float* ab2 = (const float*)d_in[10];
    const float* aW3 = (const float*)d_in[11];
    const float* ab3 = (const float*)d_in[12];
    const float* vW1 = (const float*)d_in[13];
    const float* vb1 = (const float*)d_in[14];
    const float* vW2 = (const float*)d_in[15];
    const float* vb2 = (const float*)d_in[16];
    const float* vW3 = (const float*)d_in[17];
    const float* vb3 = (const float*)d_in[18];

    __bf16* ws = (__bf16*)d_ws;
    float* out = (float*)d_out;

    hipLaunchKernelGGL(prep_kernel, dim3(PREP_TOTAL / 256), dim3(256), 0, stream,
                       sW1, sW2, sW3, aW1, aW2, aW3, vW1, vW2, vW3, ws);
    hipLaunchKernelGGL(fused_kernel, dim3(B_ / 16), dim3(512), 0, stream,
                       obs, sb1, sb2, sb3, ab1, ab2, ab3, vb1, vb2, vb3,
                       (const __bf16*)ws, out);
}